// Round 13
// baseline (140.752 us; speedup 1.0000x reference)
//
#include <hip/hip_runtime.h>

typedef unsigned short u16;
typedef unsigned int   u32;
typedef unsigned long long u64;
typedef __attribute__((ext_vector_type(8))) short bf16x8;
typedef __attribute__((ext_vector_type(4))) float f32x4;
typedef __attribute__((address_space(3))) u32 lds_u32;
typedef __attribute__((address_space(1))) u32 gbl_u32;

#define MFMA16(a,b,c) __builtin_amdgcn_mfma_f32_16x16x32_bf16((a),(b),(c),0,0,0)
#define QSCALE 0.1803368801111204f   // 0.125 * log2(e)

#define WAIT3 do{ asm volatile("s_waitcnt vmcnt(3)" ::: "memory"); }while(0)
#define WAIT4 do{ asm volatile("s_waitcnt vmcnt(4)" ::: "memory"); }while(0)
#define WAIT0 do{ asm volatile("s_waitcnt vmcnt(0)" ::: "memory"); }while(0)
#define SCHED __builtin_amdgcn_sched_barrier(0)
#define BARR  __builtin_amdgcn_s_barrier()

__device__ __forceinline__ u16 f2bf(float f){
  u32 u = __builtin_bit_cast(u32, f);
  u32 r = u + 0x7fffu + ((u>>16)&1u);
  return (u16)(r>>16);
}
__device__ __forceinline__ float bf2f(u16 h){
  return __builtin_bit_cast(float, (u32)h<<16);
}

union V8 { u16 s[8]; uint4 v; };

// ---- merged conversions: hs (3072 blocks) + 4 weights (4*288 blocks) ----
__global__ __launch_bounds__(256) void cvt_all(const float* __restrict__ hs,
    const float* __restrict__ Wq, const float* __restrict__ Wk,
    const float* __restrict__ Wv, const float* __restrict__ Wo,
    u16* __restrict__ hsb, u16* __restrict__ wqkv, u16* __restrict__ woh)
{
  const int bid = blockIdx.x;
  if (bid < 3072){
    int i = bid*256 + threadIdx.x;
    const float4* p = (const float4*)(hs + (size_t)i*8);
    float4 a = p[0], b = p[1];
    V8 t;
    t.s[0]=f2bf(a.x); t.s[1]=f2bf(a.y); t.s[2]=f2bf(a.z); t.s[3]=f2bf(a.w);
    t.s[4]=f2bf(b.x); t.s[5]=f2bf(b.y); t.s[6]=f2bf(b.z); t.s[7]=f2bf(b.w);
    *(uint4*)(hsb + (size_t)i*8) = t.v;
    return;
  }
  const int r = bid - 3072;
  const int seg = r / 288;
  const int off = (r - seg*288)*256 + threadIdx.x;
  const float* src = seg==0?Wq: seg==1?Wk: seg==2?Wv: Wo;
  const float4* p = (const float4*)(src + (size_t)off*8);
  float4 a = p[0], b = p[1];
  float xs[8] = {a.x,a.y,a.z,a.w,b.x,b.y,b.z,b.w};
  V8 t;
  #pragma unroll
  for (int j=0;j<8;++j) t.s[j]=f2bf(xs[j]);
  if (seg < 3) *(uint4*)(wqkv + (size_t)seg*589824 + (size_t)off*8) = t.v;
  else         *(uint4*)(woh  + (size_t)off*8) = t.v;
}

// ---- fused QKV GEMM: 128x256 tile, 8 waves, BK=32, 3-buffer counted-vmcnt (r11) ----
__global__ __launch_bounds__(512) void mm_qkv(const u16* __restrict__ A, const u16* __restrict__ Bp,
    const float* __restrict__ bq, const float* __restrict__ bk, const float* __restrict__ bvv,
    u16* __restrict__ Oq, u16* __restrict__ Ok, u16* __restrict__ Ov)
{
  __shared__ u16 P[3][12288];                 // 3 x 24KB
  const int bid = blockIdx.x;                 // 576
  const int sid = (bid & 7)*72 + (bid >> 3);  // XCD swizzle, m-major per XCD
  const int mb = sid/9, nb = sid - mb*9;
  const int m0 = mb*128, n0 = nb*256;
  const int tid = threadIdx.x;                // 0..511
  const int lane = tid&63, wid = tid>>6;      // 8 waves
  const int wr = wid>>2, wc = wid&3;          // 2m x 4n, wave tile 64x64
  const int fr = lane&15, fg = lane>>4;

  const char* Ab = (const char*)A;
  const char* Bb = (const char*)Bp;
  const char* sp[3];
  #pragma unroll
  for (int c=0;c<3;++c){
    int ci = c*512 + tid;
    if (ci < 512){
      int line = ci>>3, slot = ci&7;
      int d = slot ^ (line&7);
      int row = 2*line + (d>>2);
      sp[c] = Ab + (size_t)(m0+row)*1536 + (d&3)*16;
    } else {
      int i = ci - 512;
      int line = i>>3, slot = i&7;
      int d = slot ^ (line&7);
      int row = 2*line + (d>>2);
      sp[c] = Bb + (size_t)(n0+row)*1536 + (d&3)*16;
    }
  }
  const int sl = (((fr&1)<<2) + fg) ^ (fr>>1);
  const int aoff = (fr&~1)*64 + sl*16 + wr*4096;          // + mt*1024
  const int boff = 8192 + (fr&~1)*64 + sl*16 + wc*4096;   // + nt*1024

  f32x4 zz = {0.f,0.f,0.f,0.f};
  f32x4 acc[4][4];
  #pragma unroll
  for (int i=0;i<4;++i)
    #pragma unroll
    for (int j=0;j<4;++j) acc[i][j]=zz;

  auto STAGE = [&](int t, int b){
    char* dst0 = (char*)P[b];
    #pragma unroll
    for (int c=0;c<3;++c)
      __builtin_amdgcn_global_load_lds((const gbl_u32*)(sp[c] + (size_t)t*64),
        (lds_u32*)(dst0 + c*8192 + wid*1024), 16, 0, 0);
  };
  auto COMPUTE = [&](int b){
    const char* pb = (const char*)P[b];
    bf16x8 bfr[4];
    #pragma unroll
    for (int nt=0;nt<4;++nt)
      bfr[nt] = *(const bf16x8*)(pb + boff + nt*1024);
    #pragma unroll
    for (int mt=0;mt<4;++mt){
      bf16x8 af = *(const bf16x8*)(pb + aoff + mt*1024);
      #pragma unroll
      for (int nt=0;nt<4;++nt)
        acc[mt][nt] = MFMA16(af, bfr[nt], acc[mt][nt]);
    }
  };

  STAGE(0, 0); STAGE(1, 1);
  int cb = 0;
  for (int t=0; t<24; ++t){
    if (t < 23) WAIT3; else WAIT0;
    BARR; SCHED;
    if (t < 22){
      int sb = cb + 2; if (sb >= 3) sb -= 3;
      STAGE(t+2, sb);
    }
    __builtin_amdgcn_s_setprio(1);
    COMPUTE(cb);
    __builtin_amdgcn_s_setprio(0);
    cb = (cb == 2) ? 0 : cb + 1;
  }

  const int seg = nb/3;                         // 0=q 1=k 2=v
  const float* bias = seg==0?bq: seg==1?bk:bvv;
  const float sc = (seg==0) ? QSCALE : 1.0f;
  if (seg < 2){
    u16* O = seg==0?Oq:Ok;
    #pragma unroll
    for (int mt=0;mt<4;++mt){
      #pragma unroll
      for (int nt=0;nt<4;++nt){
        int colw = n0 + wc*64 + nt*16 + fr - seg*768;
        float bz = bias[colw];
        int hh = colw>>6, d = colw&63;
        #pragma unroll
        for (int rr=0;rr<4;++rr){
          int row = m0 + wr*64 + mt*16 + fg*4 + rr;
          int b = row>>10, nn = row&1023;
          O[((size_t)(b*12+hh)<<16) + (size_t)nn*64 + d] = f2bf((acc[mt][nt][rr] + bz) * sc);
        }
      }
    }
  } else {
    #pragma unroll
    for (int mt=0;mt<4;++mt){
      #pragma unroll
      for (int nt=0;nt<4;++nt){
        int colw = n0 + wc*64 + nt*16 + fr - 1536;
        float bz = bias[colw];
        int hh = colw>>6, d = colw&63;
        int row0 = m0 + wr*64 + mt*16 + fg*4;
        int b = row0>>10, nn = row0&1023;
        union { u16 h[4]; u64 q; } pk;
        #pragma unroll
        for (int rr=0;rr<4;++rr) pk.h[rr] = f2bf(acc[mt][nt][rr] + bz);
        *(u64*)&Ov[((size_t)(b*12+hh)<<16) + (size_t)d*1024 + nn] = pk.q;
      }
    }
  }
}

// ---- O-projection GEMM: single-bf16, 3-buffer pipeline, fp32 out (unchanged) ----
__global__ __launch_bounds__(256) void mm_o(const u16* __restrict__ A, const u16* __restrict__ Bp,
                                            const float* __restrict__ bias, float* __restrict__ O)
{
  __shared__ u16 P[3][8192];
  const int bid = blockIdx.x;                 // 384
  const int sid = (bid & 7)*48 + (bid >> 3);
  const int mb = sid/6, nb = sid - mb*6;
  const int m0 = mb*128, n0 = nb*128;
  const int tid = threadIdx.x;
  const int lane = tid&63, wid = tid>>6;
  const int wr = wid>>1, wc = wid&1;
  const int fr = lane&15, fg = lane>>4;

  const char* Ab = (const char*)A;
  const char* Bb = (const char*)Bp;
  const char* sp[4];
  #pragma unroll
  for (int c=0;c<4;++c){
    int ci = c*256 + tid;
    int row = ci>>3, slot = ci&7;
    int d = slot ^ (row&7);
    if (d < 4) sp[c] = Ab + (size_t)(m0+row)*1536 + d*16;
    else       sp[c] = Bb + (size_t)(n0+row)*1536 + (d-4)*16;
  }
  const int sA = (fg ^ (fr&7)) << 4;
  const int sB = sA ^ 64;

  f32x4 zz = {0.f,0.f,0.f,0.f};
  f32x4 acc[4][4];
  #pragma unroll
  for (int i=0;i<4;++i)
    #pragma unroll
    for (int j=0;j<4;++j) acc[i][j]=zz;

  auto STAGE = [&](int t, int b){
    char* dst0 = (char*)P[b];
    #pragma unroll
    for (int c=0;c<4;++c)
      __builtin_amdgcn_global_load_lds((const gbl_u32*)(sp[c] + (size_t)t*64),
        (lds_u32*)(dst0 + c*4096 + wid*1024), 16, 0, 0);
  };
  auto COMPUTE = [&](int b){
    const char* pb = (const char*)P[b];
    bf16x8 bfr[4];
    #pragma unroll
    for (int nt=0;nt<4;++nt)
      bfr[nt] = *(const bf16x8*)(pb + (wc*64+nt*16+fr)*128 + sB);
    #pragma unroll
    for (int mt=0;mt<4;++mt){
      bf16x8 af = *(const bf16x8*)(pb + (wr*64+mt*16+fr)*128 + sA);
      #pragma unroll
      for (int nt=0;nt<4;++nt)
        acc[mt][nt] = MFMA16(af, bfr[nt], acc[mt][nt]);
    }
  };

  STAGE(0, 0); STAGE(1, 1);
  int cb = 0;
  for (int t=0; t<24; ++t){
    if (t < 23) WAIT4; else WAIT0;
    BARR; SCHED;
    if (t < 22){
      int sb = cb + 2; if (sb >= 3) sb -= 3;
      STAGE(t+2, sb);
    }
    __builtin_amdgcn_s_setprio(1);
    COMPUTE(cb);
    __builtin_amdgcn_s_setprio(0);
    cb = (cb == 2) ? 0 : cb + 1;
  }

  #pragma unroll
  for (int mt=0;mt<4;++mt){
    #pragma unroll
    for (int nt=0;nt<4;++nt){
      int colb = n0 + wc*64 + nt*16 + fr;
      float bz = bias[colb];
      #pragma unroll
      for (int rr=0;rr<4;++rr){
        int row = m0 + wr*64 + mt*16 + fg*4 + rr;
        O[(size_t)row*768 + colb] = acc[mt][nt][rr] + bz;
      }
    }
  }
}

// ---- MFMA flash attention: K LDS-staged, V direct global->reg (L2-resident) ----
__global__ __launch_bounds__(256, 4) void attn(const u16* __restrict__ qh, const u16* __restrict__ kh,
                                               const u16* __restrict__ vh, u16* __restrict__ ch)
{
  __shared__ u16 Kb[2][4096];          // 16KB
  __shared__ u16 Ps[4][32][72];        // 18KB -> total 34KB -> 4 blocks/CU
  const int tid=threadIdx.x, w=tid>>6, lane=tid&63;
  const int fr=lane&15, fg=lane>>4;
  const int bh=blockIdx.x, qt=blockIdx.y;
  const size_t base=(size_t)bh<<16;
  const int q0=qt*128 + w*32;

  const char* kbase = (const char*)(kh + base);
  const u16*  vg    = vh + base;       // [64 d][1024 n]

  int koff[2];
  #pragma unroll
  for (int c=0;c<2;++c){
    int ci = c*256 + tid;
    int row = ci>>3;
    int colp = ((ci&7)*16) ^ ((row&7)<<4);
    koff[c] = row*128 + colp;
  }

  bf16x8 qf[2][2];
  #pragma unroll
  for (int mt=0;mt<2;++mt)
    #pragma unroll
    for (int ks=0;ks<2;++ks)
      qf[mt][ks] = *(const bf16x8*)&qh[base + (size_t)(q0+mt*16+fr)*64 + ks*32 + fg*8];

  const int swz = (fr&7)<<4;
  int lowD[2];
  #pragma unroll
  for (int ks=0;ks<2;++ks) lowD[ks] = (ks*64 + fg*16) ^ swz;
  const int frbase = fr*128;

  f32x4 zz = {0.f,0.f,0.f,0.f};
  f32x4 o[2][4];
  float lr[2] = {0.f, 0.f};
  #pragma unroll
  for (int mt=0;mt<2;++mt)
    #pragma unroll
    for (int j=0;j<4;++j) o[mt][j]=zz;

  {
    #pragma unroll
    for (int c=0;c<2;++c)
      __builtin_amdgcn_global_load_lds((const gbl_u32*)(kbase + koff[c]),
        (lds_u32*)((char*)&Kb[0][0] + c*4096 + w*1024), 16, 0, 0);
  }
  __syncthreads();

  for (int kt=0; kt<16; ++kt){
    const int buf = kt & 1;
    {
      const int ktn = (kt+1) & 15;
      const char* kt_ = kbase + ktn*8192;
      #pragma unroll
      for (int c=0;c<2;++c)
        __builtin_amdgcn_global_load_lds((const gbl_u32*)(kt_ + koff[c]),
          (lds_u32*)((char*)&Kb[buf^1][0] + c*4096 + w*1024), 16, 0, 0);
    }

    // V half 0 issued early: covered by QK MFMA + softmax
    bf16x8 vf0[4];
    #pragma unroll
    for (int dt=0;dt<4;++dt)
      vf0[dt] = *(const bf16x8*)&vg[(size_t)(dt*16+fr)*1024 + kt*64 + fg*8];

    // swapped QK^T: s[mt][ct] = K_tile x Q -> D[key=fg*4+rr][q=fr]
    f32x4 s[2][4];
    #pragma unroll
    for (int mt=0;mt<2;++mt)
      #pragma unroll
      for (int j=0;j<4;++j) s[mt][j]=zz;
    const char* kb = (const char*)&Kb[buf][0];
    __builtin_amdgcn_s_setprio(1);
    #pragma unroll
    for (int ct=0;ct<4;++ct){
      #pragma unroll
      for (int ks=0;ks<2;++ks){
        bf16x8 kf = *(const bf16x8*)(kb + ct*2048 + frbase + lowD[ks]);
        s[0][ct]=MFMA16(kf,qf[0][ks],s[0][ct]);
        s[1][ct]=MFMA16(kf,qf[1][ks],s[1][ct]);
      }
    }
    __builtin_amdgcn_s_setprio(0);

    // softmax: thread holds 4 consecutive keys per quad -> cvt_pk + one b64 store
    #pragma unroll
    for (int mt=0;mt<2;++mt){
      float lsum = 0.f;
      #pragma unroll
      for (int ct=0;ct<4;++ct){
        float e0 = __builtin_amdgcn_exp2f(s[mt][ct][0]);
        float e1 = __builtin_amdgcn_exp2f(s[mt][ct][1]);
        float e2 = __builtin_amdgcn_exp2f(s[mt][ct][2]);
        float e3 = __builtin_amdgcn_exp2f(s[mt][ct][3]);
        lsum += (e0+e1)+(e2+e3);
        u32 w0, w1;
        asm("v_cvt_pk_bf16_f32 %0, %1, %2" : "=v"(w0) : "v"(e0), "v"(e1));
        asm("v_cvt_pk_bf16_f32 %0, %1, %2" : "=v"(w1) : "v"(e2), "v"(e3));
        uint2 pk2; pk2.x = w0; pk2.y = w1;
        *(uint2*)&Ps[w][mt*16+fr][ct*16+fg*4] = pk2;
      }
      lr[mt] += lsum;
    }

    // V half 1 issued here: covered by PV half 0 + TLP
    bf16x8 vf1[4];
    #pragma unroll
    for (int dt=0;dt<4;++dt)
      vf1[dt] = *(const bf16x8*)&vg[(size_t)(dt*16+fr)*1024 + kt*64 + 32 + fg*8];

    __builtin_amdgcn_s_setprio(1);
    #pragma unroll
    for (int mt=0;mt<2;++mt){
      bf16x8 pa = *(const bf16x8*)&Ps[w][mt*16+fr][fg*8];
      #pragma unroll
      for (int dt=0;dt<4;++dt)
        o[mt][dt]=MFMA16(pa, vf0[dt], o[mt][dt]);
    }
    #pragma unroll
    for (int mt=0;mt<2;++mt){
      bf16x8 pa = *(const bf16x8*)&Ps[w][mt*16+fr][32+fg*8];
      #pragma unroll
      for (int dt=0;dt<4;++dt)
        o[mt][dt]=MFMA16(pa, vf1[dt], o[mt][dt]);
    }
    __builtin_amdgcn_s_setprio(0);

    __syncthreads();
  }

  float inv[2][4];
  #pragma unroll
  for (int mt=0;mt<2;++mt){
    float l = lr[mt];
    l += __shfl_xor(l,16); l += __shfl_xor(l,32);
    #pragma unroll
    for (int rr=0;rr<4;++rr)
      inv[mt][rr] = 1.0f / __shfl(l, fg*4+rr, 16);
  }
  const int b=bh/12, hd=bh%12;
  #pragma unroll
  for (int mt=0;mt<2;++mt){
    #pragma unroll
    for (int dt=0;dt<4;++dt){
      int d = dt*16 + fr;
      #pragma unroll
      for (int rr=0;rr<4;++rr){
        int n = q0 + mt*16 + fg*4 + rr;
        ch[((size_t)b*1024 + n)*768 + hd*64 + d] = f2bf(o[mt][dt][rr] * inv[mt][rr]);
      }
    }
  }
}

extern "C" void kernel_launch(void* const* d_in, const int* in_sizes, int n_in,
                              void* d_out, int out_size, void* d_ws, size_t ws_size,
                              hipStream_t stream) {
  const float* hs = (const float*)d_in[0];
  const float* Wq = (const float*)d_in[1];
  const float* bq = (const float*)d_in[2];
  const float* Wk = (const float*)d_in[3];
  const float* bk = (const float*)d_in[4];
  const float* Wv = (const float*)d_in[5];
  const float* bv = (const float*)d_in[6];
  const float* Wo = (const float*)d_in[7];
  const float* bo = (const float*)d_in[8];
  float* out = (float*)d_out;

  const size_t PS = (size_t)8192*768;
  u16* ws16  = (u16*)d_ws;
  u16* hs_bf = ws16;                        // reused as c_hi after mm_qkv
  u16* q_bf  = ws16 + PS;
  u16* k_bf  = ws16 + 2*PS;
  u16* v_bf  = ws16 + 3*PS;                 // transposed per head [bh][d][n]
  u16* wqkv  = ws16 + 4*PS;
  u16* woh   = wqkv + 3*589824;
  u16* c_hi  = hs_bf;

  dim3 blk(256);
  cvt_all<<<3072 + 4*288, blk, 0, stream>>>(hs, Wq, Wk, Wv, Wo, hs_bf, wqkv, woh);
  mm_qkv<<<576, dim3(512), 0, stream>>>(hs_bf, wqkv, bq, bk, bv, q_bf, k_bf, v_bf);
  attn<<<dim3(96,8), blk, 0, stream>>>(q_bf, k_bf, v_bf, c_hi);
  mm_o<<<384, blk, 0, stream>>>(c_hi, woh, bo, out);
}

// Round 14
// 115.953 us; speedup vs baseline: 1.2139x; 1.2139x over previous
//
#include <hip/hip_runtime.h>

typedef unsigned short u16;
typedef unsigned int   u32;
typedef unsigned long long u64;
typedef __attribute__((ext_vector_type(8))) short bf16x8;
typedef __attribute__((ext_vector_type(4))) float f32x4;
typedef __attribute__((address_space(3))) u32 lds_u32;
typedef __attribute__((address_space(1))) u32 gbl_u32;

#define MFMA16(a,b,c) __builtin_amdgcn_mfma_f32_16x16x32_bf16((a),(b),(c),0,0,0)
#define QSCALE 0.1803368801111204f   // 0.125 * log2(e)

#define WAIT3 do{ asm volatile("s_waitcnt vmcnt(3)" ::: "memory"); }while(0)
#define WAIT4 do{ asm volatile("s_waitcnt vmcnt(4)" ::: "memory"); }while(0)
#define WAIT0 do{ asm volatile("s_waitcnt vmcnt(0)" ::: "memory"); }while(0)
#define SCHED __builtin_amdgcn_sched_barrier(0)
#define BARR  __builtin_amdgcn_s_barrier()

__device__ __forceinline__ u16 f2bf(float f){
  u32 u = __builtin_bit_cast(u32, f);
  u32 r = u + 0x7fffu + ((u>>16)&1u);
  return (u16)(r>>16);
}
__device__ __forceinline__ float bf2f(u16 h){
  return __builtin_bit_cast(float, (u32)h<<16);
}

union V8 { u16 s[8]; uint4 v; };

// ---- merged conversions: hs (3072 blocks) + 4 weights (4*288 blocks) ----
__global__ __launch_bounds__(256) void cvt_all(const float* __restrict__ hs,
    const float* __restrict__ Wq, const float* __restrict__ Wk,
    const float* __restrict__ Wv, const float* __restrict__ Wo,
    u16* __restrict__ hsb, u16* __restrict__ wqkv, u16* __restrict__ woh)
{
  const int bid = blockIdx.x;
  if (bid < 3072){
    int i = bid*256 + threadIdx.x;
    const float4* p = (const float4*)(hs + (size_t)i*8);
    float4 a = p[0], b = p[1];
    V8 t;
    t.s[0]=f2bf(a.x); t.s[1]=f2bf(a.y); t.s[2]=f2bf(a.z); t.s[3]=f2bf(a.w);
    t.s[4]=f2bf(b.x); t.s[5]=f2bf(b.y); t.s[6]=f2bf(b.z); t.s[7]=f2bf(b.w);
    *(uint4*)(hsb + (size_t)i*8) = t.v;
    return;
  }
  const int r = bid - 3072;
  const int seg = r / 288;
  const int off = (r - seg*288)*256 + threadIdx.x;
  const float* src = seg==0?Wq: seg==1?Wk: seg==2?Wv: Wo;
  const float4* p = (const float4*)(src + (size_t)off*8);
  float4 a = p[0], b = p[1];
  float xs[8] = {a.x,a.y,a.z,a.w,b.x,b.y,b.z,b.w};
  V8 t;
  #pragma unroll
  for (int j=0;j<8;++j) t.s[j]=f2bf(xs[j]);
  if (seg < 3) *(uint4*)(wqkv + (size_t)seg*589824 + (size_t)off*8) = t.v;
  else         *(uint4*)(woh  + (size_t)off*8) = t.v;
}

// ---- fused QKV GEMM: 128x256 tile, 8 waves, BK=32, 3-buffer counted-vmcnt (r11) ----
__global__ __launch_bounds__(512) void mm_qkv(const u16* __restrict__ A, const u16* __restrict__ Bp,
    const float* __restrict__ bq, const float* __restrict__ bk, const float* __restrict__ bvv,
    u16* __restrict__ Oq, u16* __restrict__ Ok, u16* __restrict__ Ov)
{
  __shared__ u16 P[3][12288];                 // 3 x 24KB
  const int bid = blockIdx.x;                 // 576
  const int sid = (bid & 7)*72 + (bid >> 3);  // XCD swizzle, m-major per XCD
  const int mb = sid/9, nb = sid - mb*9;
  const int m0 = mb*128, n0 = nb*256;
  const int tid = threadIdx.x;                // 0..511
  const int lane = tid&63, wid = tid>>6;      // 8 waves
  const int wr = wid>>2, wc = wid&3;          // 2m x 4n, wave tile 64x64
  const int fr = lane&15, fg = lane>>4;

  const char* Ab = (const char*)A;
  const char* Bb = (const char*)Bp;
  const char* sp[3];
  #pragma unroll
  for (int c=0;c<3;++c){
    int ci = c*512 + tid;
    if (ci < 512){
      int line = ci>>3, slot = ci&7;
      int d = slot ^ (line&7);
      int row = 2*line + (d>>2);
      sp[c] = Ab + (size_t)(m0+row)*1536 + (d&3)*16;
    } else {
      int i = ci - 512;
      int line = i>>3, slot = i&7;
      int d = slot ^ (line&7);
      int row = 2*line + (d>>2);
      sp[c] = Bb + (size_t)(n0+row)*1536 + (d&3)*16;
    }
  }
  const int sl = (((fr&1)<<2) + fg) ^ (fr>>1);
  const int aoff = (fr&~1)*64 + sl*16 + wr*4096;          // + mt*1024
  const int boff = 8192 + (fr&~1)*64 + sl*16 + wc*4096;   // + nt*1024

  f32x4 zz = {0.f,0.f,0.f,0.f};
  f32x4 acc[4][4];
  #pragma unroll
  for (int i=0;i<4;++i)
    #pragma unroll
    for (int j=0;j<4;++j) acc[i][j]=zz;

  auto STAGE = [&](int t, int b){
    char* dst0 = (char*)P[b];
    #pragma unroll
    for (int c=0;c<3;++c)
      __builtin_amdgcn_global_load_lds((const gbl_u32*)(sp[c] + (size_t)t*64),
        (lds_u32*)(dst0 + c*8192 + wid*1024), 16, 0, 0);
  };
  auto COMPUTE = [&](int b){
    const char* pb = (const char*)P[b];
    bf16x8 bfr[4];
    #pragma unroll
    for (int nt=0;nt<4;++nt)
      bfr[nt] = *(const bf16x8*)(pb + boff + nt*1024);
    #pragma unroll
    for (int mt=0;mt<4;++mt){
      bf16x8 af = *(const bf16x8*)(pb + aoff + mt*1024);
      #pragma unroll
      for (int nt=0;nt<4;++nt)
        acc[mt][nt] = MFMA16(af, bfr[nt], acc[mt][nt]);
    }
  };

  STAGE(0, 0); STAGE(1, 1);
  int cb = 0;
  for (int t=0; t<24; ++t){
    if (t < 23) WAIT3; else WAIT0;
    BARR; SCHED;
    if (t < 22){
      int sb = cb + 2; if (sb >= 3) sb -= 3;
      STAGE(t+2, sb);
    }
    __builtin_amdgcn_s_setprio(1);
    COMPUTE(cb);
    __builtin_amdgcn_s_setprio(0);
    cb = (cb == 2) ? 0 : cb + 1;
  }

  const int seg = nb/3;                         // 0=q 1=k 2=v
  const float* bias = seg==0?bq: seg==1?bk:bvv;
  const float sc = (seg==0) ? QSCALE : 1.0f;
  if (seg < 2){
    u16* O = seg==0?Oq:Ok;
    #pragma unroll
    for (int mt=0;mt<4;++mt){
      #pragma unroll
      for (int nt=0;nt<4;++nt){
        int colw = n0 + wc*64 + nt*16 + fr - seg*768;
        float bz = bias[colw];
        int hh = colw>>6, d = colw&63;
        #pragma unroll
        for (int rr=0;rr<4;++rr){
          int row = m0 + wr*64 + mt*16 + fg*4 + rr;
          int b = row>>10, nn = row&1023;
          O[((size_t)(b*12+hh)<<16) + (size_t)nn*64 + d] = f2bf((acc[mt][nt][rr] + bz) * sc);
        }
      }
    }
  } else {
    #pragma unroll
    for (int mt=0;mt<4;++mt){
      #pragma unroll
      for (int nt=0;nt<4;++nt){
        int colw = n0 + wc*64 + nt*16 + fr - 1536;
        float bz = bias[colw];
        int hh = colw>>6, d = colw&63;
        int row0 = m0 + wr*64 + mt*16 + fg*4;
        int b = row0>>10, nn = row0&1023;
        union { u16 h[4]; u64 q; } pk;
        #pragma unroll
        for (int rr=0;rr<4;++rr) pk.h[rr] = f2bf(acc[mt][nt][rr] + bz);
        *(u64*)&Ov[((size_t)(b*12+hh)<<16) + (size_t)d*1024 + nn] = pk.q;
      }
    }
  }
}

// ---- O-projection GEMM: single-bf16, 3-buffer pipeline, fp32 out (unchanged) ----
__global__ __launch_bounds__(256) void mm_o(const u16* __restrict__ A, const u16* __restrict__ Bp,
                                            const float* __restrict__ bias, float* __restrict__ O)
{
  __shared__ u16 P[3][8192];
  const int bid = blockIdx.x;                 // 384
  const int sid = (bid & 7)*48 + (bid >> 3);
  const int mb = sid/6, nb = sid - mb*6;
  const int m0 = mb*128, n0 = nb*128;
  const int tid = threadIdx.x;
  const int lane = tid&63, wid = tid>>6;
  const int wr = wid>>1, wc = wid&1;
  const int fr = lane&15, fg = lane>>4;

  const char* Ab = (const char*)A;
  const char* Bb = (const char*)Bp;
  const char* sp[4];
  #pragma unroll
  for (int c=0;c<4;++c){
    int ci = c*256 + tid;
    int row = ci>>3, slot = ci&7;
    int d = slot ^ (row&7);
    if (d < 4) sp[c] = Ab + (size_t)(m0+row)*1536 + d*16;
    else       sp[c] = Bb + (size_t)(n0+row)*1536 + (d-4)*16;
  }
  const int sA = (fg ^ (fr&7)) << 4;
  const int sB = sA ^ 64;

  f32x4 zz = {0.f,0.f,0.f,0.f};
  f32x4 acc[4][4];
  #pragma unroll
  for (int i=0;i<4;++i)
    #pragma unroll
    for (int j=0;j<4;++j) acc[i][j]=zz;

  auto STAGE = [&](int t, int b){
    char* dst0 = (char*)P[b];
    #pragma unroll
    for (int c=0;c<4;++c)
      __builtin_amdgcn_global_load_lds((const gbl_u32*)(sp[c] + (size_t)t*64),
        (lds_u32*)(dst0 + c*4096 + wid*1024), 16, 0, 0);
  };
  auto COMPUTE = [&](int b){
    const char* pb = (const char*)P[b];
    bf16x8 bfr[4];
    #pragma unroll
    for (int nt=0;nt<4;++nt)
      bfr[nt] = *(const bf16x8*)(pb + (wc*64+nt*16+fr)*128 + sB);
    #pragma unroll
    for (int mt=0;mt<4;++mt){
      bf16x8 af = *(const bf16x8*)(pb + (wr*64+mt*16+fr)*128 + sA);
      #pragma unroll
      for (int nt=0;nt<4;++nt)
        acc[mt][nt] = MFMA16(af, bfr[nt], acc[mt][nt]);
    }
  };

  STAGE(0, 0); STAGE(1, 1);
  int cb = 0;
  for (int t=0; t<24; ++t){
    if (t < 23) WAIT4; else WAIT0;
    BARR; SCHED;
    if (t < 22){
      int sb = cb + 2; if (sb >= 3) sb -= 3;
      STAGE(t+2, sb);
    }
    __builtin_amdgcn_s_setprio(1);
    COMPUTE(cb);
    __builtin_amdgcn_s_setprio(0);
    cb = (cb == 2) ? 0 : cb + 1;
  }

  #pragma unroll
  for (int mt=0;mt<4;++mt){
    #pragma unroll
    for (int nt=0;nt<4;++nt){
      int colb = n0 + wc*64 + nt*16 + fr;
      float bz = bias[colb];
      #pragma unroll
      for (int rr=0;rr<4;++rr){
        int row = m0 + wr*64 + mt*16 + fg*4 + rr;
        O[(size_t)row*768 + colb] = acc[mt][nt][rr] + bz;
      }
    }
  }
}

// ---- MFMA flash attention: 256 q-rows/block, 8 waves, K/V LDS double-buffered ----
__global__ __launch_bounds__(512) void attn(const u16* __restrict__ qh, const u16* __restrict__ kh,
                                            const u16* __restrict__ vh, u16* __restrict__ ch)
{
  __shared__ u16 Kb[2][4096];          // 16KB
  __shared__ u16 Vb[2][4096];          // 16KB
  __shared__ u16 Ps[8][32][72];        // 36KB -> total 68KB -> 2 blocks/CU
  const int tid=threadIdx.x, w=tid>>6, lane=tid&63;
  const int fr=lane&15, fg=lane>>4;
  const int bh=blockIdx.x, qt=blockIdx.y;
  const size_t base=(size_t)bh<<16;
  const int q0=qt*256 + w*32;

  const char* kbase = (const char*)(kh + base);
  const char* vbase = (const char*)(vh + base);

  // single stage chunk per thread (512 threads cover 8KB per tile)
  const int srow = tid>>3;
  const int scolp = ((tid&7)*16) ^ ((srow&7)<<4);
  const int koff = srow*128  + scolp;
  const int voff = srow*2048 + scolp;
  const int ldst = tid*16;

  bf16x8 qf[2][2];
  #pragma unroll
  for (int mt=0;mt<2;++mt)
    #pragma unroll
    for (int ks=0;ks<2;++ks)
      qf[mt][ks] = *(const bf16x8*)&qh[base + (size_t)(q0+mt*16+fr)*64 + ks*32 + fg*8];

  const int swz = (fr&7)<<4;
  int lowD[2];
  #pragma unroll
  for (int ks=0;ks<2;++ks) lowD[ks] = (ks*64 + fg*16) ^ swz;
  const int frbase = fr*128;

  f32x4 zz = {0.f,0.f,0.f,0.f};
  f32x4 o[2][4];
  float lr[2] = {0.f, 0.f};
  #pragma unroll
  for (int mt=0;mt<2;++mt)
    #pragma unroll
    for (int j=0;j<4;++j) o[mt][j]=zz;

  __builtin_amdgcn_global_load_lds((const gbl_u32*)(kbase + koff),
    (lds_u32*)((char*)&Kb[0][0] + ldst), 16, 0, 0);
  __builtin_amdgcn_global_load_lds((const gbl_u32*)(vbase + voff),
    (lds_u32*)((char*)&Vb[0][0] + ldst), 16, 0, 0);
  __syncthreads();

  for (int kt=0; kt<16; ++kt){
    const int buf = kt & 1;
    {
      const int ktn = (kt+1) & 15;
      __builtin_amdgcn_global_load_lds((const gbl_u32*)(kbase + ktn*8192 + koff),
        (lds_u32*)((char*)&Kb[buf^1][0] + ldst), 16, 0, 0);
      __builtin_amdgcn_global_load_lds((const gbl_u32*)(vbase + ktn*128 + voff),
        (lds_u32*)((char*)&Vb[buf^1][0] + ldst), 16, 0, 0);
    }

    // swapped QK^T: s[mt][ct] = K_tile x Q -> D[key=fg*4+rr][q=fr]
    f32x4 s[2][4];
    #pragma unroll
    for (int mt=0;mt<2;++mt)
      #pragma unroll
      for (int j=0;j<4;++j) s[mt][j]=zz;
    const char* kb = (const char*)&Kb[buf][0];
    __builtin_amdgcn_s_setprio(1);
    #pragma unroll
    for (int ct=0;ct<4;++ct){
      #pragma unroll
      for (int ks=0;ks<2;++ks){
        bf16x8 kf = *(const bf16x8*)(kb + ct*2048 + frbase + lowD[ks]);
        s[0][ct]=MFMA16(kf,qf[0][ks],s[0][ct]);
        s[1][ct]=MFMA16(kf,qf[1][ks],s[1][ct]);
      }
    }
    __builtin_amdgcn_s_setprio(0);

    // softmax: 4 consecutive keys per quad -> cvt_pk + one b64 store per (mt,ct)
    #pragma unroll
    for (int mt=0;mt<2;++mt){
      float lsum = 0.f;
      #pragma unroll
      for (int ct=0;ct<4;++ct){
        float e0 = __builtin_amdgcn_exp2f(s[mt][ct][0]);
        float e1 = __builtin_amdgcn_exp2f(s[mt][ct][1]);
        float e2 = __builtin_amdgcn_exp2f(s[mt][ct][2]);
        float e3 = __builtin_amdgcn_exp2f(s[mt][ct][3]);
        lsum += (e0+e1)+(e2+e3);
        u32 w0, w1;
        asm("v_cvt_pk_bf16_f32 %0, %1, %2" : "=v"(w0) : "v"(e0), "v"(e1));
        asm("v_cvt_pk_bf16_f32 %0, %1, %2" : "=v"(w1) : "v"(e2), "v"(e3));
        uint2 pk2; pk2.x = w0; pk2.y = w1;
        *(uint2*)&Ps[w][mt*16+fr][ct*16+fg*4] = pk2;
      }
      lr[mt] += lsum;
    }

    // PV from LDS
    const char* vb = (const char*)&Vb[buf][0];
    __builtin_amdgcn_s_setprio(1);
    #pragma unroll
    for (int ks2=0;ks2<2;++ks2){
      bf16x8 vf[4];
      #pragma unroll
      for (int dt=0;dt<4;++dt)
        vf[dt] = *(const bf16x8*)(vb + dt*2048 + frbase + lowD[ks2]);
      #pragma unroll
      for (int mt=0;mt<2;++mt){
        bf16x8 pa = *(const bf16x8*)&Ps[w][mt*16+fr][ks2*32+fg*8];
        #pragma unroll
        for (int dt=0;dt<4;++dt)
          o[mt][dt]=MFMA16(pa, vf[dt], o[mt][dt]);
      }
    }
    __builtin_amdgcn_s_setprio(0);

    __syncthreads();
  }

  float inv[2][4];
  #pragma unroll
  for (int mt=0;mt<2;++mt){
    float l = lr[mt];
    l += __shfl_xor(l,16); l += __shfl_xor(l,32);
    #pragma unroll
    for (int rr=0;rr<4;++rr)
      inv[mt][rr] = 1.0f / __shfl(l, fg*4+rr, 16);
  }
  const int b=bh/12, hd=bh%12;
  #pragma unroll
  for (int mt=0;mt<2;++mt){
    #pragma unroll
    for (int dt=0;dt<4;++dt){
      int d = dt*16 + fr;
      #pragma unroll
      for (int rr=0;rr<4;++rr){
        int n = q0 + mt*16 + fg*4 + rr;
        ch[((size_t)b*1024 + n)*768 + hd*64 + d] = f2bf(o[mt][dt][rr] * inv[mt][rr]);
      }
    }
  }
}

extern "C" void kernel_launch(void* const* d_in, const int* in_sizes, int n_in,
                              void* d_out, int out_size, void* d_ws, size_t ws_size,
                              hipStream_t stream) {
  const float* hs = (const float*)d_in[0];
  const float* Wq = (const float*)d_in[1];
  const float* bq = (const float*)d_in[2];
  const float* Wk = (const float*)d_in[3];
  const float* bk = (const float*)d_in[4];
  const float* Wv = (const float*)d_in[5];
  const float* bv = (const float*)d_in[6];
  const float* Wo = (const float*)d_in[7];
  const float* bo = (const float*)d_in[8];
  float* out = (float*)d_out;

  const size_t PS = (size_t)8192*768;
  u16* ws16  = (u16*)d_ws;
  u16* hs_bf = ws16;                        // reused as c_hi after mm_qkv
  u16* q_bf  = ws16 + PS;
  u16* k_bf  = ws16 + 2*PS;
  u16* v_bf  = ws16 + 3*PS;                 // transposed per head [bh][d][n]
  u16* wqkv  = ws16 + 4*PS;
  u16* woh   = wqkv + 3*589824;
  u16* c_hi  = hs_bf;

  dim3 blk(256);
  cvt_all<<<3072 + 4*288, blk, 0, stream>>>(hs, Wq, Wk, Wv, Wo, hs_bf, wqkv, woh);
  mm_qkv<<<576, dim3(512), 0, stream>>>(hs_bf, wqkv, bq, bk, bv, q_bf, k_bf, v_bf);
  attn<<<dim3(96,4), dim3(512), 0, stream>>>(q_bf, k_bf, v_bf, c_hi);
  mm_o<<<384, blk, 0, stream>>>(c_hi, woh, bo, out);
}

// Round 15
// 115.265 us; speedup vs baseline: 1.2211x; 1.0060x over previous
//
#include <hip/hip_runtime.h>

typedef unsigned short u16;
typedef unsigned int   u32;
typedef unsigned long long u64;
typedef __attribute__((ext_vector_type(8))) short bf16x8;
typedef __attribute__((ext_vector_type(4))) float f32x4;
typedef __attribute__((address_space(3))) u32 lds_u32;
typedef __attribute__((address_space(1))) u32 gbl_u32;

#define MFMA16(a,b,c) __builtin_amdgcn_mfma_f32_16x16x32_bf16((a),(b),(c),0,0,0)
#define QSCALE 0.1803368801111204f   // 0.125 * log2(e)

#define WAIT3 do{ asm volatile("s_waitcnt vmcnt(3)" ::: "memory"); }while(0)
#define WAIT4 do{ asm volatile("s_waitcnt vmcnt(4)" ::: "memory"); }while(0)
#define WAIT0 do{ asm volatile("s_waitcnt vmcnt(0)" ::: "memory"); }while(0)
#define SCHED __builtin_amdgcn_sched_barrier(0)
#define BARR  __builtin_amdgcn_s_barrier()

__device__ __forceinline__ u16 f2bf(float f){
  u32 u = __builtin_bit_cast(u32, f);
  u32 r = u + 0x7fffu + ((u>>16)&1u);
  return (u16)(r>>16);
}
__device__ __forceinline__ float bf2f(u16 h){
  return __builtin_bit_cast(float, (u32)h<<16);
}

union V8 { u16 s[8]; uint4 v; };

// ---- merged conversions: hs (3072 blocks) + 4 weights (4*288 blocks) ----
__global__ __launch_bounds__(256) void cvt_all(const float* __restrict__ hs,
    const float* __restrict__ Wq, const float* __restrict__ Wk,
    const float* __restrict__ Wv, const float* __restrict__ Wo,
    u16* __restrict__ hsb, u16* __restrict__ wqkv, u16* __restrict__ woh)
{
  const int bid = blockIdx.x;
  if (bid < 3072){
    int i = bid*256 + threadIdx.x;
    const float4* p = (const float4*)(hs + (size_t)i*8);
    float4 a = p[0], b = p[1];
    V8 t;
    t.s[0]=f2bf(a.x); t.s[1]=f2bf(a.y); t.s[2]=f2bf(a.z); t.s[3]=f2bf(a.w);
    t.s[4]=f2bf(b.x); t.s[5]=f2bf(b.y); t.s[6]=f2bf(b.z); t.s[7]=f2bf(b.w);
    *(uint4*)(hsb + (size_t)i*8) = t.v;
    return;
  }
  const int r = bid - 3072;
  const int seg = r / 288;
  const int off = (r - seg*288)*256 + threadIdx.x;
  const float* src = seg==0?Wq: seg==1?Wk: seg==2?Wv: Wo;
  const float4* p = (const float4*)(src + (size_t)off*8);
  float4 a = p[0], b = p[1];
  float xs[8] = {a.x,a.y,a.z,a.w,b.x,b.y,b.z,b.w};
  V8 t;
  #pragma unroll
  for (int j=0;j<8;++j) t.s[j]=f2bf(xs[j]);
  if (seg < 3) *(uint4*)(wqkv + (size_t)seg*589824 + (size_t)off*8) = t.v;
  else         *(uint4*)(woh  + (size_t)off*8) = t.v;
}

// ---- fused QKV GEMM: 128x256 tile, 8 waves, BK=32, 3-buffer counted-vmcnt (r11) ----
__global__ __launch_bounds__(512) void mm_qkv(const u16* __restrict__ A, const u16* __restrict__ Bp,
    const float* __restrict__ bq, const float* __restrict__ bk, const float* __restrict__ bvv,
    u16* __restrict__ Oq, u16* __restrict__ Ok, u16* __restrict__ Ov)
{
  __shared__ u16 P[3][12288];                 // 3 x 24KB
  const int bid = blockIdx.x;                 // 576
  const int sid = (bid & 7)*72 + (bid >> 3);  // XCD swizzle, m-major per XCD
  const int mb = sid/9, nb = sid - mb*9;
  const int m0 = mb*128, n0 = nb*256;
  const int tid = threadIdx.x;                // 0..511
  const int lane = tid&63, wid = tid>>6;      // 8 waves
  const int wr = wid>>2, wc = wid&3;          // 2m x 4n, wave tile 64x64
  const int fr = lane&15, fg = lane>>4;

  const char* Ab = (const char*)A;
  const char* Bb = (const char*)Bp;
  const char* sp[3];
  #pragma unroll
  for (int c=0;c<3;++c){
    int ci = c*512 + tid;
    if (ci < 512){
      int line = ci>>3, slot = ci&7;
      int d = slot ^ (line&7);
      int row = 2*line + (d>>2);
      sp[c] = Ab + (size_t)(m0+row)*1536 + (d&3)*16;
    } else {
      int i = ci - 512;
      int line = i>>3, slot = i&7;
      int d = slot ^ (line&7);
      int row = 2*line + (d>>2);
      sp[c] = Bb + (size_t)(n0+row)*1536 + (d&3)*16;
    }
  }
  const int sl = (((fr&1)<<2) + fg) ^ (fr>>1);
  const int aoff = (fr&~1)*64 + sl*16 + wr*4096;          // + mt*1024
  const int boff = 8192 + (fr&~1)*64 + sl*16 + wc*4096;   // + nt*1024

  f32x4 zz = {0.f,0.f,0.f,0.f};
  f32x4 acc[4][4];
  #pragma unroll
  for (int i=0;i<4;++i)
    #pragma unroll
    for (int j=0;j<4;++j) acc[i][j]=zz;

  auto STAGE = [&](int t, int b){
    char* dst0 = (char*)P[b];
    #pragma unroll
    for (int c=0;c<3;++c)
      __builtin_amdgcn_global_load_lds((const gbl_u32*)(sp[c] + (size_t)t*64),
        (lds_u32*)(dst0 + c*8192 + wid*1024), 16, 0, 0);
  };
  auto COMPUTE = [&](int b){
    const char* pb = (const char*)P[b];
    bf16x8 bfr[4];
    #pragma unroll
    for (int nt=0;nt<4;++nt)
      bfr[nt] = *(const bf16x8*)(pb + boff + nt*1024);
    #pragma unroll
    for (int mt=0;mt<4;++mt){
      bf16x8 af = *(const bf16x8*)(pb + aoff + mt*1024);
      #pragma unroll
      for (int nt=0;nt<4;++nt)
        acc[mt][nt] = MFMA16(af, bfr[nt], acc[mt][nt]);
    }
  };

  STAGE(0, 0); STAGE(1, 1);
  int cb = 0;
  for (int t=0; t<24; ++t){
    if (t < 23) WAIT3; else WAIT0;
    BARR; SCHED;
    if (t < 22){
      int sb = cb + 2; if (sb >= 3) sb -= 3;
      STAGE(t+2, sb);
    }
    __builtin_amdgcn_s_setprio(1);
    COMPUTE(cb);
    __builtin_amdgcn_s_setprio(0);
    cb = (cb == 2) ? 0 : cb + 1;
  }

  const int seg = nb/3;                         // 0=q 1=k 2=v
  const float* bias = seg==0?bq: seg==1?bk:bvv;
  const float sc = (seg==0) ? QSCALE : 1.0f;
  if (seg < 2){
    u16* O = seg==0?Oq:Ok;
    #pragma unroll
    for (int mt=0;mt<4;++mt){
      #pragma unroll
      for (int nt=0;nt<4;++nt){
        int colw = n0 + wc*64 + nt*16 + fr - seg*768;
        float bz = bias[colw];
        int hh = colw>>6, d = colw&63;
        #pragma unroll
        for (int rr=0;rr<4;++rr){
          int row = m0 + wr*64 + mt*16 + fg*4 + rr;
          int b = row>>10, nn = row&1023;
          O[((size_t)(b*12+hh)<<16) + (size_t)nn*64 + d] = f2bf((acc[mt][nt][rr] + bz) * sc);
        }
      }
    }
  } else {
    #pragma unroll
    for (int mt=0;mt<4;++mt){
      #pragma unroll
      for (int nt=0;nt<4;++nt){
        int colw = n0 + wc*64 + nt*16 + fr - 1536;
        float bz = bias[colw];
        int hh = colw>>6, d = colw&63;
        int row0 = m0 + wr*64 + mt*16 + fg*4;
        int b = row0>>10, nn = row0&1023;
        union { u16 h[4]; u64 q; } pk;
        #pragma unroll
        for (int rr=0;rr<4;++rr) pk.h[rr] = f2bf(acc[mt][nt][rr] + bz);
        *(u64*)&Ov[((size_t)(b*12+hh)<<16) + (size_t)d*1024 + nn] = pk.q;
      }
    }
  }
}

// ---- O-projection GEMM: single-bf16, 3-buffer pipeline, fp32 out (unchanged) ----
__global__ __launch_bounds__(256) void mm_o(const u16* __restrict__ A, const u16* __restrict__ Bp,
                                            const float* __restrict__ bias, float* __restrict__ O)
{
  __shared__ u16 P[3][8192];
  const int bid = blockIdx.x;                 // 384
  const int sid = (bid & 7)*48 + (bid >> 3);
  const int mb = sid/6, nb = sid - mb*6;
  const int m0 = mb*128, n0 = nb*128;
  const int tid = threadIdx.x;
  const int lane = tid&63, wid = tid>>6;
  const int wr = wid>>1, wc = wid&1;
  const int fr = lane&15, fg = lane>>4;

  const char* Ab = (const char*)A;
  const char* Bb = (const char*)Bp;
  const char* sp[4];
  #pragma unroll
  for (int c=0;c<4;++c){
    int ci = c*256 + tid;
    int row = ci>>3, slot = ci&7;
    int d = slot ^ (row&7);
    if (d < 4) sp[c] = Ab + (size_t)(m0+row)*1536 + d*16;
    else       sp[c] = Bb + (size_t)(n0+row)*1536 + (d-4)*16;
  }
  const int sA = (fg ^ (fr&7)) << 4;
  const int sB = sA ^ 64;

  f32x4 zz = {0.f,0.f,0.f,0.f};
  f32x4 acc[4][4];
  #pragma unroll
  for (int i=0;i<4;++i)
    #pragma unroll
    for (int j=0;j<4;++j) acc[i][j]=zz;

  auto STAGE = [&](int t, int b){
    char* dst0 = (char*)P[b];
    #pragma unroll
    for (int c=0;c<4;++c)
      __builtin_amdgcn_global_load_lds((const gbl_u32*)(sp[c] + (size_t)t*64),
        (lds_u32*)(dst0 + c*4096 + wid*1024), 16, 0, 0);
  };
  auto COMPUTE = [&](int b){
    const char* pb = (const char*)P[b];
    bf16x8 bfr[4];
    #pragma unroll
    for (int nt=0;nt<4;++nt)
      bfr[nt] = *(const bf16x8*)(pb + (wc*64+nt*16+fr)*128 + sB);
    #pragma unroll
    for (int mt=0;mt<4;++mt){
      bf16x8 af = *(const bf16x8*)(pb + (wr*64+mt*16+fr)*128 + sA);
      #pragma unroll
      for (int nt=0;nt<4;++nt)
        acc[mt][nt] = MFMA16(af, bfr[nt], acc[mt][nt]);
    }
  };

  STAGE(0, 0); STAGE(1, 1);
  int cb = 0;
  for (int t=0; t<24; ++t){
    if (t < 23) WAIT4; else WAIT0;
    BARR; SCHED;
    if (t < 22){
      int sb = cb + 2; if (sb >= 3) sb -= 3;
      STAGE(t+2, sb);
    }
    __builtin_amdgcn_s_setprio(1);
    COMPUTE(cb);
    __builtin_amdgcn_s_setprio(0);
    cb = (cb == 2) ? 0 : cb + 1;
  }

  #pragma unroll
  for (int mt=0;mt<4;++mt){
    #pragma unroll
    for (int nt=0;nt<4;++nt){
      int colb = n0 + wc*64 + nt*16 + fr;
      float bz = bias[colb];
      #pragma unroll
      for (int rr=0;rr<4;++rr){
        int row = m0 + wr*64 + mt*16 + fg*4 + rr;
        O[(size_t)row*768 + colb] = acc[mt][nt][rr] + bz;
      }
    }
  }
}

// ---- MFMA flash attention: 4 waves x 64 q-rows (2.7 MFMA/LDS-read), l via ones-MFMA ----
__global__ __launch_bounds__(256, 2) void attn(const u16* __restrict__ qh, const u16* __restrict__ kh,
                                               const u16* __restrict__ vh, u16* __restrict__ ch)
{
  __shared__ u16 Kb[2][4096];          // 16KB
  __shared__ u16 Vb[2][4096];          // 16KB
  __shared__ u16 Ps[4][64][72];        // 36KB -> total 68KB -> 2 blocks/CU
  const int tid=threadIdx.x, w=tid>>6, lane=tid&63;
  const int fr=lane&15, fg=lane>>4;
  const int bh=blockIdx.x, qt=blockIdx.y;
  const size_t base=(size_t)bh<<16;
  const int q0=qt*256 + w*64;

  const char* kbase = (const char*)(kh + base);
  const char* vbase = (const char*)(vh + base);

  int koff[2], voff[2];
  #pragma unroll
  for (int c=0;c<2;++c){
    int ci = c*256 + tid;
    int row = ci>>3;
    int colp = ((ci&7)*16) ^ ((row&7)<<4);
    koff[c] = row*128  + colp;
    voff[c] = row*2048 + colp;
  }

  bf16x8 qf[4][2];
  #pragma unroll
  for (int mt=0;mt<4;++mt)
    #pragma unroll
    for (int ks=0;ks<2;++ks)
      qf[mt][ks] = *(const bf16x8*)&qh[base + (size_t)(q0+mt*16+fr)*64 + ks*32 + fg*8];

  const int swz = (fr&7)<<4;
  int lowD[2];
  #pragma unroll
  for (int ks=0;ks<2;++ks) lowD[ks] = (ks*64 + fg*16) ^ swz;
  const int frbase = fr*128;

  const short one_bf = (short)0x3F80;   // bf16 1.0
  bf16x8 ones = {one_bf,one_bf,one_bf,one_bf,one_bf,one_bf,one_bf,one_bf};

  f32x4 zz = {0.f,0.f,0.f,0.f};
  f32x4 o[4][4];
  f32x4 ol[4];                          // l accumulator (rows fg*4+rr, broadcast over fr)
  #pragma unroll
  for (int mt=0;mt<4;++mt){
    ol[mt]=zz;
    #pragma unroll
    for (int j=0;j<4;++j) o[mt][j]=zz;
  }

  {
    #pragma unroll
    for (int c=0;c<2;++c){
      __builtin_amdgcn_global_load_lds((const gbl_u32*)(kbase + koff[c]),
        (lds_u32*)((char*)&Kb[0][0] + c*4096 + w*1024), 16, 0, 0);
      __builtin_amdgcn_global_load_lds((const gbl_u32*)(vbase + voff[c]),
        (lds_u32*)((char*)&Vb[0][0] + c*4096 + w*1024), 16, 0, 0);
    }
  }
  __syncthreads();

  for (int kt=0; kt<16; ++kt){
    const int buf = kt & 1;
    {
      const int ktn = (kt+1) & 15;
      const char* kt_ = kbase + ktn*8192;
      const char* vt_ = vbase + ktn*128;
      #pragma unroll
      for (int c=0;c<2;++c){
        __builtin_amdgcn_global_load_lds((const gbl_u32*)(kt_ + koff[c]),
          (lds_u32*)((char*)&Kb[buf^1][0] + c*4096 + w*1024), 16, 0, 0);
        __builtin_amdgcn_global_load_lds((const gbl_u32*)(vt_ + voff[c]),
          (lds_u32*)((char*)&Vb[buf^1][0] + c*4096 + w*1024), 16, 0, 0);
      }
    }

    // swapped QK^T: s[mt][ct] = K_tile x Q -> D[key=fg*4+rr][q=fr]
    f32x4 s[4][4];
    #pragma unroll
    for (int mt=0;mt<4;++mt)
      #pragma unroll
      for (int j=0;j<4;++j) s[mt][j]=zz;
    const char* kb = (const char*)&Kb[buf][0];
    __builtin_amdgcn_s_setprio(1);
    #pragma unroll
    for (int ct=0;ct<4;++ct){
      #pragma unroll
      for (int ks=0;ks<2;++ks){
        bf16x8 kf = *(const bf16x8*)(kb + ct*2048 + frbase + lowD[ks]);
        #pragma unroll
        for (int mt=0;mt<4;++mt)
          s[mt][ct]=MFMA16(kf,qf[mt][ks],s[mt][ct]);
      }
    }
    __builtin_amdgcn_s_setprio(0);

    // softmax: 4 consecutive keys per quad -> cvt_pk + one b64 store per (mt,ct)
    #pragma unroll
    for (int mt=0;mt<4;++mt){
      #pragma unroll
      for (int ct=0;ct<4;++ct){
        float e0 = __builtin_amdgcn_exp2f(s[mt][ct][0]);
        float e1 = __builtin_amdgcn_exp2f(s[mt][ct][1]);
        float e2 = __builtin_amdgcn_exp2f(s[mt][ct][2]);
        float e3 = __builtin_amdgcn_exp2f(s[mt][ct][3]);
        u32 w0, w1;
        asm("v_cvt_pk_bf16_f32 %0, %1, %2" : "=v"(w0) : "v"(e0), "v"(e1));
        asm("v_cvt_pk_bf16_f32 %0, %1, %2" : "=v"(w1) : "v"(e2), "v"(e3));
        uint2 pk2; pk2.x = w0; pk2.y = w1;
        *(uint2*)&Ps[w][mt*16+fr][ct*16+fg*4] = pk2;
      }
    }

    // PV from LDS; l accumulated via ones B-fragment (free row-sum on matrix pipe)
    const char* vb = (const char*)&Vb[buf][0];
    __builtin_amdgcn_s_setprio(1);
    #pragma unroll
    for (int ks2=0;ks2<2;++ks2){
      bf16x8 vf[4];
      #pragma unroll
      for (int dt=0;dt<4;++dt)
        vf[dt] = *(const bf16x8*)(vb + dt*2048 + frbase + lowD[ks2]);
      #pragma unroll
      for (int mt=0;mt<4;++mt){
        bf16x8 pa = *(const bf16x8*)&Ps[w][mt*16+fr][ks2*32+fg*8];
        #pragma unroll
        for (int dt=0;dt<4;++dt)
          o[mt][dt]=MFMA16(pa, vf[dt], o[mt][dt]);
        ol[mt]=MFMA16(pa, ones, ol[mt]);
      }
    }
    __builtin_amdgcn_s_setprio(0);

    __syncthreads();
  }

  const int b=bh/12, hd=bh%12;
  #pragma unroll
  for (int mt=0;mt<4;++mt){
    float inv[4];
    #pragma unroll
    for (int rr=0;rr<4;++rr) inv[rr] = 1.0f / ol[mt][rr];
    #pragma unroll
    for (int dt=0;dt<4;++dt){
      int d = dt*16 + fr;
      #pragma unroll
      for (int rr=0;rr<4;++rr){
        int n = q0 + mt*16 + fg*4 + rr;
        ch[((size_t)b*1024 + n)*768 + hd*64 + d] = f2bf(o[mt][dt][rr] * inv[rr]);
      }
    }
  }
}

extern "C" void kernel_launch(void* const* d_in, const int* in_sizes, int n_in,
                              void* d_out, int out_size, void* d_ws, size_t ws_size,
                              hipStream_t stream) {
  const float* hs = (const float*)d_in[0];
  const float* Wq = (const float*)d_in[1];
  const float* bq = (const float*)d_in[2];
  const float* Wk = (const float*)d_in[3];
  const float* bk = (const float*)d_in[4];
  const float* Wv = (const float*)d_in[5];
  const float* bv = (const float*)d_in[6];
  const float* Wo = (const float*)d_in[7];
  const float* bo = (const float*)d_in[8];
  float* out = (float*)d_out;

  const size_t PS = (size_t)8192*768;
  u16* ws16  = (u16*)d_ws;
  u16* hs_bf = ws16;                        // reused as c_hi after mm_qkv
  u16* q_bf  = ws16 + PS;
  u16* k_bf  = ws16 + 2*PS;
  u16* v_bf  = ws16 + 3*PS;                 // transposed per head [bh][d][n]
  u16* wqkv  = ws16 + 4*PS;
  u16* woh   = wqkv + 3*589824;
  u16* c_hi  = hs_bf;

  dim3 blk(256);
  cvt_all<<<3072 + 4*288, blk, 0, stream>>>(hs, Wq, Wk, Wv, Wo, hs_bf, wqkv, woh);
  mm_qkv<<<576, dim3(512), 0, stream>>>(hs_bf, wqkv, bq, bk, bv, q_bf, k_bf, v_bf);
  attn<<<dim3(96,4), blk, 0, stream>>>(q_bf, k_bf, v_bf, c_hi);
  mm_o<<<384, blk, 0, stream>>>(c_hi, woh, bo, out);
}

// Round 16
// 110.216 us; speedup vs baseline: 1.2771x; 1.0458x over previous
//
#include <hip/hip_runtime.h>

typedef unsigned short u16;
typedef unsigned int   u32;
typedef unsigned long long u64;
typedef __attribute__((ext_vector_type(8))) short bf16x8;
typedef __attribute__((ext_vector_type(4))) float f32x4;
typedef __attribute__((address_space(3))) u32 lds_u32;
typedef __attribute__((address_space(1))) u32 gbl_u32;

#define MFMA16(a,b,c) __builtin_amdgcn_mfma_f32_16x16x32_bf16((a),(b),(c),0,0,0)
#define QSCALE 0.1803368801111204f   // 0.125 * log2(e)

#define WAIT5 do{ asm volatile("s_waitcnt vmcnt(5)" ::: "memory"); }while(0)
#define WAIT4 do{ asm volatile("s_waitcnt vmcnt(4)" ::: "memory"); }while(0)
#define WAIT0 do{ asm volatile("s_waitcnt vmcnt(0)" ::: "memory"); }while(0)
#define SCHED __builtin_amdgcn_sched_barrier(0)
#define BARR  __builtin_amdgcn_s_barrier()

__device__ __forceinline__ u16 f2bf(float f){
  u32 u = __builtin_bit_cast(u32, f);
  u32 r = u + 0x7fffu + ((u>>16)&1u);
  return (u16)(r>>16);
}
__device__ __forceinline__ float bf2f(u16 h){
  return __builtin_bit_cast(float, (u32)h<<16);
}

union V8 { u16 s[8]; uint4 v; };

// ---- merged conversions: hs (3072 blocks) + 4 weights (4*288 blocks) ----
__global__ __launch_bounds__(256) void cvt_all(const float* __restrict__ hs,
    const float* __restrict__ Wq, const float* __restrict__ Wk,
    const float* __restrict__ Wv, const float* __restrict__ Wo,
    u16* __restrict__ hsb, u16* __restrict__ wqkv, u16* __restrict__ woh)
{
  const int bid = blockIdx.x;
  if (bid < 3072){
    int i = bid*256 + threadIdx.x;
    const float4* p = (const float4*)(hs + (size_t)i*8);
    float4 a = p[0], b = p[1];
    V8 t;
    t.s[0]=f2bf(a.x); t.s[1]=f2bf(a.y); t.s[2]=f2bf(a.z); t.s[3]=f2bf(a.w);
    t.s[4]=f2bf(b.x); t.s[5]=f2bf(b.y); t.s[6]=f2bf(b.z); t.s[7]=f2bf(b.w);
    *(uint4*)(hsb + (size_t)i*8) = t.v;
    return;
  }
  const int r = bid - 3072;
  const int seg = r / 288;
  const int off = (r - seg*288)*256 + threadIdx.x;
  const float* src = seg==0?Wq: seg==1?Wk: seg==2?Wv: Wo;
  const float4* p = (const float4*)(src + (size_t)off*8);
  float4 a = p[0], b = p[1];
  float xs[8] = {a.x,a.y,a.z,a.w,b.x,b.y,b.z,b.w};
  V8 t;
  #pragma unroll
  for (int j=0;j<8;++j) t.s[j]=f2bf(xs[j]);
  if (seg < 3) *(uint4*)(wqkv + (size_t)seg*589824 + (size_t)off*8) = t.v;
  else         *(uint4*)(woh  + (size_t)off*8) = t.v;
}

// ---- fused QKV GEMM: 128x192 tile, 4 waves (64x96 each), BK=32, 3-buffer counted-vmcnt
// grid 64x12 = 768 blocks = exactly 3 per CU (2 resident, 60KB LDS) -> balanced makespan.
// LDS line (128B) = row pair [2r|2r+1] as 8x16B slots, chunk d at slot d^(r&7).
// A region 64 lines (8KB) @0; B region 96 lines (12KB) @8192. 20KB/buffer.
__global__ __launch_bounds__(256) void mm_qkv(const u16* __restrict__ A, const u16* __restrict__ Bp,
    const float* __restrict__ bq, const float* __restrict__ bk, const float* __restrict__ bvv,
    u16* __restrict__ Oq, u16* __restrict__ Ok, u16* __restrict__ Ov)
{
  __shared__ u16 P[3][10240];                 // 3 x 20KB
  const int bid = blockIdx.x;                 // 768
  const int sid = (bid & 7)*96 + (bid >> 3);  // XCD swizzle, m-major per XCD
  const int mb = sid/12, nb = sid - mb*12;
  const int m0 = mb*128, n0 = nb*192;
  const int tid = threadIdx.x;                // 0..255
  const int lane = tid&63, wid = tid>>6;      // 4 waves
  const int wr = wid>>1, wc = wid&1;          // 2m x 2n, wave tile 64x96
  const int fr = lane&15, fg = lane>>4;

  // stage sources: 5 chunks/thread (A: ci<512, B: ci>=512)
  const char* Ab = (const char*)A;
  const char* Bb = (const char*)Bp;
  const char* sp[5];
  #pragma unroll
  for (int c=0;c<5;++c){
    int ci = c*256 + tid;
    if (ci < 512){
      int line = ci>>3, slot = ci&7;
      int d = slot ^ (line&7);
      int row = 2*line + (d>>2);
      sp[c] = Ab + (size_t)(m0+row)*1536 + (d&3)*16;
    } else {
      int i = ci - 512;                       // 0..767, 96 B-lines
      int line = i>>3, slot = i&7;
      int d = slot ^ (line&7);
      int row = 2*line + (d>>2);
      sp[c] = Bb + (size_t)(n0+row)*1536 + (d&3)*16;
    }
  }
  const int sl = (((fr&1)<<2) + fg) ^ (fr>>1);
  const int aoff = (fr&~1)*64 + sl*16 + wr*4096;          // + mt*1024, mt=0..3
  const int boff = 8192 + (fr&~1)*64 + sl*16 + wc*6144;   // + nt*1024, nt=0..5

  f32x4 zz = {0.f,0.f,0.f,0.f};
  f32x4 acc[4][6];
  #pragma unroll
  for (int i=0;i<4;++i)
    #pragma unroll
    for (int j=0;j<6;++j) acc[i][j]=zz;

  auto STAGE = [&](int t, int b){
    char* dst0 = (char*)P[b];
    #pragma unroll
    for (int c=0;c<5;++c)
      __builtin_amdgcn_global_load_lds((const gbl_u32*)(sp[c] + (size_t)t*64),
        (lds_u32*)(dst0 + c*4096 + tid*16), 16, 0, 0);
  };
  auto COMPUTE = [&](int b){
    const char* pb = (const char*)P[b];
    bf16x8 bfr[6];
    #pragma unroll
    for (int nt=0;nt<6;++nt)
      bfr[nt] = *(const bf16x8*)(pb + boff + nt*1024);
    #pragma unroll
    for (int mt=0;mt<4;++mt){
      bf16x8 af = *(const bf16x8*)(pb + aoff + mt*1024);
      #pragma unroll
      for (int nt=0;nt<6;++nt)
        acc[mt][nt] = MFMA16(af, bfr[nt], acc[mt][nt]);
    }
  };

  STAGE(0, 0); STAGE(1, 1);
  int cb = 0;
  for (int t=0; t<24; ++t){
    if (t < 23) WAIT5; else WAIT0;
    BARR; SCHED;
    if (t < 22){
      int sb = cb + 2; if (sb >= 3) sb -= 3;
      STAGE(t+2, sb);
    }
    __builtin_amdgcn_s_setprio(1);
    COMPUTE(cb);
    __builtin_amdgcn_s_setprio(0);
    cb = (cb == 2) ? 0 : cb + 1;
  }

  const int seg = nb/4;                         // 0=q 1=k 2=v (192*4 = 768)
  const float* bias = seg==0?bq: seg==1?bk:bvv;
  const float sc = (seg==0) ? QSCALE : 1.0f;
  if (seg < 2){
    u16* O = seg==0?Oq:Ok;
    #pragma unroll
    for (int mt=0;mt<4;++mt){
      #pragma unroll
      for (int nt=0;nt<6;++nt){
        int colw = n0 + wc*96 + nt*16 + fr - seg*768;
        float bz = bias[colw];
        int hh = colw>>6, d = colw&63;
        #pragma unroll
        for (int rr=0;rr<4;++rr){
          int row = m0 + wr*64 + mt*16 + fg*4 + rr;
          int b = row>>10, nn = row&1023;
          O[((size_t)(b*12+hh)<<16) + (size_t)nn*64 + d] = f2bf((acc[mt][nt][rr] + bz) * sc);
        }
      }
    }
  } else {
    #pragma unroll
    for (int mt=0;mt<4;++mt){
      #pragma unroll
      for (int nt=0;nt<6;++nt){
        int colw = n0 + wc*96 + nt*16 + fr - 1536;
        float bz = bias[colw];
        int hh = colw>>6, d = colw&63;
        int row0 = m0 + wr*64 + mt*16 + fg*4;
        int b = row0>>10, nn = row0&1023;
        union { u16 h[4]; u64 q; } pk;
        #pragma unroll
        for (int rr=0;rr<4;++rr) pk.h[rr] = f2bf(acc[mt][nt][rr] + bz);
        *(u64*)&Ov[((size_t)(b*12+hh)<<16) + (size_t)d*1024 + nn] = pk.q;
      }
    }
  }
}

// ---- O-projection GEMM: single-bf16, 3-buffer pipeline, fp32 out (unchanged) ----
__global__ __launch_bounds__(256) void mm_o(const u16* __restrict__ A, const u16* __restrict__ Bp,
                                            const float* __restrict__ bias, float* __restrict__ O)
{
  __shared__ u16 P[3][8192];
  const int bid = blockIdx.x;                 // 384
  const int sid = (bid & 7)*48 + (bid >> 3);
  const int mb = sid/6, nb = sid - mb*6;
  const int m0 = mb*128, n0 = nb*128;
  const int tid = threadIdx.x;
  const int lane = tid&63, wid = tid>>6;
  const int wr = wid>>1, wc = wid&1;
  const int fr = lane&15, fg = lane>>4;

  const char* Ab = (const char*)A;
  const char* Bb = (const char*)Bp;
  const char* sp[4];
  #pragma unroll
  for (int c=0;c<4;++c){
    int ci = c*256 + tid;
    int row = ci>>3, slot = ci&7;
    int d = slot ^ (row&7);
    if (d < 4) sp[c] = Ab + (size_t)(m0+row)*1536 + d*16;
    else       sp[c] = Bb + (size_t)(n0+row)*1536 + (d-4)*16;
  }
  const int sA = (fg ^ (fr&7)) << 4;
  const int sB = sA ^ 64;

  f32x4 zz = {0.f,0.f,0.f,0.f};
  f32x4 acc[4][4];
  #pragma unroll
  for (int i=0;i<4;++i)
    #pragma unroll
    for (int j=0;j<4;++j) acc[i][j]=zz;

  auto STAGE = [&](int t, int b){
    char* dst0 = (char*)P[b];
    #pragma unroll
    for (int c=0;c<4;++c)
      __builtin_amdgcn_global_load_lds((const gbl_u32*)(sp[c] + (size_t)t*64),
        (lds_u32*)(dst0 + c*4096 + wid*1024), 16, 0, 0);
  };
  auto COMPUTE = [&](int b){
    const char* pb = (const char*)P[b];
    bf16x8 bfr[4];
    #pragma unroll
    for (int nt=0;nt<4;++nt)
      bfr[nt] = *(const bf16x8*)(pb + (wc*64+nt*16+fr)*128 + sB);
    #pragma unroll
    for (int mt=0;mt<4;++mt){
      bf16x8 af = *(const bf16x8*)(pb + (wr*64+mt*16+fr)*128 + sA);
      #pragma unroll
      for (int nt=0;nt<4;++nt)
        acc[mt][nt] = MFMA16(af, bfr[nt], acc[mt][nt]);
    }
  };

  STAGE(0, 0); STAGE(1, 1);
  int cb = 0;
  for (int t=0; t<24; ++t){
    if (t < 23) WAIT4; else WAIT0;
    BARR; SCHED;
    if (t < 22){
      int sb = cb + 2; if (sb >= 3) sb -= 3;
      STAGE(t+2, sb);
    }
    __builtin_amdgcn_s_setprio(1);
    COMPUTE(cb);
    __builtin_amdgcn_s_setprio(0);
    cb = (cb == 2) ? 0 : cb + 1;
  }

  #pragma unroll
  for (int mt=0;mt<4;++mt){
    #pragma unroll
    for (int nt=0;nt<4;++nt){
      int colb = n0 + wc*64 + nt*16 + fr;
      float bz = bias[colb];
      #pragma unroll
      for (int rr=0;rr<4;++rr){
        int row = m0 + wr*64 + mt*16 + fg*4 + rr;
        O[(size_t)row*768 + colb] = acc[mt][nt][rr] + bz;
      }
    }
  }
}

// ---- MFMA flash attention: 4 waves x 64 q-rows, l via ones-MFMA (r15, unchanged) ----
__global__ __launch_bounds__(256, 2) void attn(const u16* __restrict__ qh, const u16* __restrict__ kh,
                                               const u16* __restrict__ vh, u16* __restrict__ ch)
{
  __shared__ u16 Kb[2][4096];          // 16KB
  __shared__ u16 Vb[2][4096];          // 16KB
  __shared__ u16 Ps[4][64][72];        // 36KB -> total 68KB -> 2 blocks/CU
  const int tid=threadIdx.x, w=tid>>6, lane=tid&63;
  const int fr=lane&15, fg=lane>>4;
  const int bh=blockIdx.x, qt=blockIdx.y;
  const size_t base=(size_t)bh<<16;
  const int q0=qt*256 + w*64;

  const char* kbase = (const char*)(kh + base);
  const char* vbase = (const char*)(vh + base);

  int koff[2], voff[2];
  #pragma unroll
  for (int c=0;c<2;++c){
    int ci = c*256 + tid;
    int row = ci>>3;
    int colp = ((ci&7)*16) ^ ((row&7)<<4);
    koff[c] = row*128  + colp;
    voff[c] = row*2048 + colp;
  }

  bf16x8 qf[4][2];
  #pragma unroll
  for (int mt=0;mt<4;++mt)
    #pragma unroll
    for (int ks=0;ks<2;++ks)
      qf[mt][ks] = *(const bf16x8*)&qh[base + (size_t)(q0+mt*16+fr)*64 + ks*32 + fg*8];

  const int swz = (fr&7)<<4;
  int lowD[2];
  #pragma unroll
  for (int ks=0;ks<2;++ks) lowD[ks] = (ks*64 + fg*16) ^ swz;
  const int frbase = fr*128;

  const short one_bf = (short)0x3F80;   // bf16 1.0
  bf16x8 ones = {one_bf,one_bf,one_bf,one_bf,one_bf,one_bf,one_bf,one_bf};

  f32x4 zz = {0.f,0.f,0.f,0.f};
  f32x4 o[4][4];
  f32x4 ol[4];
  #pragma unroll
  for (int mt=0;mt<4;++mt){
    ol[mt]=zz;
    #pragma unroll
    for (int j=0;j<4;++j) o[mt][j]=zz;
  }

  {
    #pragma unroll
    for (int c=0;c<2;++c){
      __builtin_amdgcn_global_load_lds((const gbl_u32*)(kbase + koff[c]),
        (lds_u32*)((char*)&Kb[0][0] + c*4096 + w*1024), 16, 0, 0);
      __builtin_amdgcn_global_load_lds((const gbl_u32*)(vbase + voff[c]),
        (lds_u32*)((char*)&Vb[0][0] + c*4096 + w*1024), 16, 0, 0);
    }
  }
  __syncthreads();

  for (int kt=0; kt<16; ++kt){
    const int buf = kt & 1;
    {
      const int ktn = (kt+1) & 15;
      const char* kt_ = kbase + ktn*8192;
      const char* vt_ = vbase + ktn*128;
      #pragma unroll
      for (int c=0;c<2;++c){
        __builtin_amdgcn_global_load_lds((const gbl_u32*)(kt_ + koff[c]),
          (lds_u32*)((char*)&Kb[buf^1][0] + c*4096 + w*1024), 16, 0, 0);
        __builtin_amdgcn_global_load_lds((const gbl_u32*)(vt_ + voff[c]),
          (lds_u32*)((char*)&Vb[buf^1][0] + c*4096 + w*1024), 16, 0, 0);
      }
    }

    // swapped QK^T: s[mt][ct] = K_tile x Q -> D[key=fg*4+rr][q=fr]
    f32x4 s[4][4];
    #pragma unroll
    for (int mt=0;mt<4;++mt)
      #pragma unroll
      for (int j=0;j<4;++j) s[mt][j]=zz;
    const char* kb = (const char*)&Kb[buf][0];
    __builtin_amdgcn_s_setprio(1);
    #pragma unroll
    for (int ct=0;ct<4;++ct){
      #pragma unroll
      for (int ks=0;ks<2;++ks){
        bf16x8 kf = *(const bf16x8*)(kb + ct*2048 + frbase + lowD[ks]);
        #pragma unroll
        for (int mt=0;mt<4;++mt)
          s[mt][ct]=MFMA16(kf,qf[mt][ks],s[mt][ct]);
      }
    }
    __builtin_amdgcn_s_setprio(0);

    // softmax: 4 consecutive keys per quad -> cvt_pk + one b64 store per (mt,ct)
    #pragma unroll
    for (int mt=0;mt<4;++mt){
      #pragma unroll
      for (int ct=0;ct<4;++ct){
        float e0 = __builtin_amdgcn_exp2f(s[mt][ct][0]);
        float e1 = __builtin_amdgcn_exp2f(s[mt][ct][1]);
        float e2 = __builtin_amdgcn_exp2f(s[mt][ct][2]);
        float e3 = __builtin_amdgcn_exp2f(s[mt][ct][3]);
        u32 w0, w1;
        asm("v_cvt_pk_bf16_f32 %0, %1, %2" : "=v"(w0) : "v"(e0), "v"(e1));
        asm("v_cvt_pk_bf16_f32 %0, %1, %2" : "=v"(w1) : "v"(e2), "v"(e3));
        uint2 pk2; pk2.x = w0; pk2.y = w1;
        *(uint2*)&Ps[w][mt*16+fr][ct*16+fg*4] = pk2;
      }
    }

    // PV from LDS; l accumulated via ones B-fragment
    const char* vb = (const char*)&Vb[buf][0];
    __builtin_amdgcn_s_setprio(1);
    #pragma unroll
    for (int ks2=0;ks2<2;++ks2){
      bf16x8 vf[4];
      #pragma unroll
      for (int dt=0;dt<4;++dt)
        vf[dt] = *(const bf16x8*)(vb + dt*2048 + frbase + lowD[ks2]);
      #pragma unroll
      for (int mt=0;mt<4;++mt){
        bf16x8 pa = *(const bf16x8*)&Ps[w][mt*16+fr][ks2*32+fg*8];
        #pragma unroll
        for (int dt=0;dt<4;++dt)
          o[mt][dt]=MFMA16(pa, vf[dt], o[mt][dt]);
        ol[mt]=MFMA16(pa, ones, ol[mt]);
      }
    }
    __builtin_amdgcn_s_setprio(0);

    __syncthreads();
  }

  const int b=bh/12, hd=bh%12;
  #pragma unroll
  for (int mt=0;mt<4;++mt){
    float inv[4];
    #pragma unroll
    for (int rr=0;rr<4;++rr) inv[rr] = 1.0f / ol[mt][rr];
    #pragma unroll
    for (int dt=0;dt<4;++dt){
      int d = dt*16 + fr;
      #pragma unroll
      for (int rr=0;rr<4;++rr){
        int n = q0 + mt*16 + fg*4 + rr;
        ch[((size_t)b*1024 + n)*768 + hd*64 + d] = f2bf(o[mt][dt][rr] * inv[rr]);
      }
    }
  }
}

extern "C" void kernel_launch(void* const* d_in, const int* in_sizes, int n_in,
                              void* d_out, int out_size, void* d_ws, size_t ws_size,
                              hipStream_t stream) {
  const float* hs = (const float*)d_in[0];
  const float* Wq = (const float*)d_in[1];
  const float* bq = (const float*)d_in[2];
  const float* Wk = (const float*)d_in[3];
  const float* bk = (const float*)d_in[4];
  const float* Wv = (const float*)d_in[5];
  const float* bv = (const float*)d_in[6];
  const float* Wo = (const float*)d_in[7];
  const float* bo = (const float*)d_in[8];
  float* out = (float*)d_out;

  const size_t PS = (size_t)8192*768;
  u16* ws16  = (u16*)d_ws;
  u16* hs_bf = ws16;                        // reused as c_hi after mm_qkv
  u16* q_bf  = ws16 + PS;
  u16* k_bf  = ws16 + 2*PS;
  u16* v_bf  = ws16 + 3*PS;                 // transposed per head [bh][d][n]
  u16* wqkv  = ws16 + 4*PS;
  u16* woh   = wqkv + 3*589824;
  u16* c_hi  = hs_bf;

  dim3 blk(256);
  cvt_all<<<3072 + 4*288, blk, 0, stream>>>(hs, Wq, Wk, Wv, Wo, hs_bf, wqkv, woh);
  mm_qkv<<<768, blk, 0, stream>>>(hs_bf, wqkv, bq, bk, bv, q_bf, k_bf, v_bf);
  attn<<<dim3(96,4), blk, 0, stream>>>(q_bf, k_bf, v_bf, c_hi);
  mm_o<<<384, blk, 0, stream>>>(c_hi, woh, bo, out);
}